// Round 3
// baseline (320.887 us; speedup 1.0000x reference)
//
#include <hip/hip_runtime.h>
#include <stdint.h>

// LinearAttention fused: qkv GEMM + dual softmax + linear attention + Wout GEMM + LayerNorm2d
// Shapes: b=32, c=128, n=64*64=4096, heads=4, dim_head=32.
// All GEMMs via v_mfma_f32_16x16x32_bf16 (fp32 accum).
//
// R2: atomic-free (R1 k1 spun ~395us in fp32 atomicAdd CAS loops).
// R3: load batching. R2 k1 had VGPR_Count=44 -> compiler serialized wq frag
// loads (load->wait->mfma per pair, full L2 latency each). Now: compile-time
// rp arms, explicit batched frag loads, batched x staging, vector S reads,
// __launch_bounds__ VGPR cap 128 (keeps 2 blocks/CU). k2 32->256 blocks.

constexpr int B_   = 32;
constexpr int C_   = 128;
constexpr int N_   = 4096;
constexpr int O3_  = 384;   // 3*128 qkv rows
constexpr int NSUB = 4;     // 64-wide n-subtiles per k1 block
constexpr int TPB_ = 16;    // k1 blocks per batch (4096 / 256)

using short8  = __attribute__((ext_vector_type(8))) short;
using short4v = __attribute__((ext_vector_type(4))) short;
using float4v = __attribute__((ext_vector_type(4))) float;

__device__ __forceinline__ unsigned short bf16_rne(float f) {
    union { float f; uint32_t u; } v; v.f = f;
    uint32_t u = v.u;
    u += 0x7FFFu + ((u >> 16) & 1u);   // round-to-nearest-even
    return (unsigned short)(u >> 16);
}
__device__ __forceinline__ float bf2f(unsigned short h) {
    union { uint32_t u; float f; } v; v.u = ((uint32_t)h) << 16; return v.f;
}

// workspace layout (bytes)
constexpr size_t OFF_WQ   = 0;          // Wqkv bf16: 384*128*2 = 98304
constexpr size_t OFF_WO   = 98304;      // Wout bf16: 128*128*2 = 32768
constexpr size_t OFF_SP   = 131072;     // S partials [b][16][128] f32: 262144
constexpr size_t OFF_CTXP = 393216;     // ctx partials [b][16][4096] f32: 8388608
constexpr size_t OFF_CTXN = 8781824;    // ctx normalized bf16 [b][h*32+e][d]: 262144
constexpr size_t OFF_QSM  = 9043968;    // q-softmax bf16 [b][n][h*32+d]: 33554432
// total 42,598,400 bytes

__global__ __launch_bounds__(256) void k0_prep(const float* __restrict__ Wqkv,
                                               const float* __restrict__ Wout,
                                               unsigned short* __restrict__ wq,
                                               unsigned short* __restrict__ wo) {
    int t = blockIdx.x * 256 + threadIdx.x;      // grid = 192*256 = 49152
    if (t < O3_ * C_) wq[t] = bf16_rne(Wqkv[t]);
    if (t < C_ * C_)  wo[t] = bf16_rne(Wout[t]);
}

// K1: per (b, 256-wide n-tile): for each 64-subtile: qkv = Wqkv @ x, q-softmax -> qsm,
// exp(k), v -> LDS, context accumulated in registers (MFMA). Partials to global at end.
__global__ __launch_bounds__(512, 4) void k1_qkv(const float* __restrict__ x,
                                                 const unsigned short* __restrict__ wq,
                                                 unsigned short* __restrict__ qsm,
                                                 float* __restrict__ ctx_part,
                                                 float* __restrict__ S_part) {
    __shared__ __align__(16) unsigned short xs[64 * 136];    // [n][c], stride 136
    __shared__ __align__(16) unsigned short ek[128 * 72];    // [h*32+d][n], stride 72
    __shared__ __align__(16) unsigned short vsh[128 * 72];   // [h*32+e][n]

    const int b    = blockIdx.y;
    const int tblk = blockIdx.x;                 // 0..15
    const int tid  = threadIdx.x;

    const int lane = tid & 63;
    const int wv   = tid >> 6;                   // 0..7
    const int l15  = lane & 15;
    const int quad = lane >> 4;
    const int cw   = wv & 3;                     // n col-tile within the 64
    const int ncol = cw * 16 + l15;
    const bool armA = (wv >> 2) == 0;            // waves 0-3: rp 0..5; waves 4-7: rp 6..11

    const float4v zero = {0.f, 0.f, 0.f, 0.f};
    float4v cacc[2] = {zero, zero};              // this wave's 2 context tiles
    float s_acc = 0.f;                           // this thread's S partial

    for (int s = 0; s < NSUB; s++) {
        const int ns = (tblk * NSUB + s) * 64;
        __syncthreads();                         // protect xs/ek/vsh from prev readers

        {   // stage x (fp32 global, coalesced along n) -> bf16 LDS [n][c]
            const int nl = tid & 63;
            const int cg = tid >> 6;             // 8 groups of 16 c
            const float* xp = x + ((size_t)b * C_ + (size_t)cg * 16) * N_ + ns + nl;
            float xv[16];
            #pragma unroll
            for (int i = 0; i < 16; i++) xv[i] = xp[(size_t)i * N_];   // batched, 16 in flight
            unsigned short* dst = &xs[nl * 136 + cg * 16];
            #pragma unroll
            for (int i = 0; i < 2; i++) {
                short8 v8;
                #pragma unroll
                for (int j = 0; j < 8; j++) v8[j] = (short)bf16_rne(xv[i * 8 + j]);
                *(short8*)(dst + i * 8) = v8;
            }
        }
        __syncthreads();

        // B-frags (x) loaded once, reused for all row-pairs: B[k=c][col=n]
        short8 bfx[4];
        #pragma unroll
        for (int kk = 0; kk < 4; kk++)
            bfx[kk] = *(const short8*)&xs[ncol * 136 + kk * 32 + quad * 8];

        // one row-pair GEMM: batched A-frag loads, then 8 MFMAs
        auto gemm_rp = [&](int rp, float4v& acc0, float4v& acc1) {
            const unsigned short* wqp = wq + (rp * 32 + l15) * C_ + quad * 8;
            short8 a0[4], a1[4];
            #pragma unroll
            for (int kk = 0; kk < 4; kk++) {
                a0[kk] = *(const short8*)(wqp + kk * 32);
                a1[kk] = *(const short8*)(wqp + 16 * C_ + kk * 32);
            }
            #pragma unroll
            for (int kk = 0; kk < 4; kk++) {
                acc0 = __builtin_amdgcn_mfma_f32_16x16x32_bf16(a0[kk], bfx[kk], acc0, 0, 0, 0);
                acc1 = __builtin_amdgcn_mfma_f32_16x16x32_bf16(a1[kk], bfx[kk], acc1, 0, 0, 0);
            }
        };
        // C/D layout: col = l15 (n), row = quad*4 + r (acc0: d 0..15, acc1: d 16..31)
        auto q_epi = [&](int h, const float4v& acc0, const float4v& acc1) {
            float e0[4], e1[4], z = 0.f;
            #pragma unroll
            for (int r = 0; r < 4; r++) {
                e0[r] = __expf(acc0[r]); e1[r] = __expf(acc1[r]);
                z += e0[r] + e1[r];
            }
            z += __shfl_xor(z, 16, 64);
            z += __shfl_xor(z, 32, 64);
            const float iz = 1.0f / z;
            unsigned short* qp = qsm + ((size_t)b * N_ + ns + ncol) * C_ + h * 32 + quad * 4;
            short4v s0, s1;
            #pragma unroll
            for (int r = 0; r < 4; r++) {
                s0[r] = (short)bf16_rne(e0[r] * iz);
                s1[r] = (short)bf16_rne(e1[r] * iz);
            }
            *(short4v*)qp = s0;                  // d = quad*4..+3
            *(short4v*)(qp + 16) = s1;           // d = 16+quad*4..+3
        };
        auto k_epi = [&](int h, const float4v& acc0, const float4v& acc1) {
            const int row0 = h * 32 + quad * 4;
            #pragma unroll
            for (int r = 0; r < 4; r++) {
                ek[(row0 + r) * 72 + ncol]      = bf16_rne(__expf(acc0[r]));
                ek[(row0 + 16 + r) * 72 + ncol] = bf16_rne(__expf(acc1[r]));
            }
        };
        auto v_epi = [&](int h, const float4v& acc0, const float4v& acc1) {
            const int row0 = h * 32 + quad * 4;
            #pragma unroll
            for (int r = 0; r < 4; r++) {
                vsh[(row0 + r) * 72 + ncol]      = bf16_rne(acc0[r]);
                vsh[(row0 + 16 + r) * 72 + ncol] = bf16_rne(acc1[r]);
            }
        };

        if (armA) {                              // compile-time rp in each arm
            #pragma unroll
            for (int u = 0; u < 4; u++) {        // q heads 0..3
                float4v acc0 = zero, acc1 = zero;
                gemm_rp(u, acc0, acc1);
                q_epi(u, acc0, acc1);
            }
            #pragma unroll
            for (int u = 0; u < 2; u++) {        // k heads 0,1
                float4v acc0 = zero, acc1 = zero;
                gemm_rp(4 + u, acc0, acc1);
                k_epi(u, acc0, acc1);
            }
        } else {
            #pragma unroll
            for (int u = 0; u < 2; u++) {        // k heads 2,3
                float4v acc0 = zero, acc1 = zero;
                gemm_rp(6 + u, acc0, acc1);
                k_epi(2 + u, acc0, acc1);
            }
            #pragma unroll
            for (int u = 0; u < 4; u++) {        // v heads 0..3
                float4v acc0 = zero, acc1 = zero;
                gemm_rp(8 + u, acc0, acc1);
                v_epi(u, acc0, acc1);
            }
        }
        __syncthreads();

        // context: cacc[d][e] += sum_n expk[d][n] * v[e][n]  (MFMA, K = 64)
        #pragma unroll
        for (int i = 0; i < 2; i++) {
            const int t = wv * 2 + i;            // 16 tiles: (h, d-tile, e-tile)
            const int h = t >> 2, dt = (t >> 1) & 1, et = t & 1;
            const unsigned short* ap = &ek[(h * 32 + dt * 16 + l15) * 72 + quad * 8];
            const unsigned short* bp = &vsh[(h * 32 + et * 16 + l15) * 72 + quad * 8];
            #pragma unroll
            for (int kk = 0; kk < 2; kk++) {
                short8 a  = *(const short8*)(ap + kk * 32);
                short8 bb = *(const short8*)(bp + kk * 32);
                cacc[i] = __builtin_amdgcn_mfma_f32_16x16x32_bf16(a, bb, cacc[i], 0, 0, 0);
            }
        }

        {   // S partial sums (same bf16 values the context MFMA consumed)
            const int row = tid >> 2;            // 0..127 = h*32+d
            const int sub = tid & 3;
            const unsigned short* ep = &ek[row * 72 + sub * 16];
            short8 e0 = *(const short8*)ep;      // 2 x ds_read_b128
            short8 e1 = *(const short8*)(ep + 8);
            float ss = 0.f;
            #pragma unroll
            for (int j = 0; j < 8; j++) ss += bf2f((unsigned short)e0[j]) + bf2f((unsigned short)e1[j]);
            s_acc += ss;
        }
    }

    // write-out: plain stores, no atomics
    float* cp_base = ctx_part + ((size_t)(b * TPB_ + tblk) << 12);
    #pragma unroll
    for (int i = 0; i < 2; i++) {
        const int t = wv * 2 + i;
        const int h = t >> 2, dt = (t >> 1) & 1, et = t & 1;
        float* cp = cp_base + ((h * 32 + dt * 16 + quad * 4) * 32 + et * 16 + l15);
        #pragma unroll
        for (int r = 0; r < 4; r++) cp[r * 32] = cacc[i][r];
    }
    {
        float ss = s_acc;
        ss += __shfl_xor(ss, 1, 64);
        ss += __shfl_xor(ss, 2, 64);
        if ((tid & 3) == 0)
            S_part[(size_t)(b * TPB_ + tblk) * 128 + (tid >> 2)] = ss;
    }
}

// K2: reduce 16 partials per b, fold 1/S, emit bf16 context in A-frag layout [b][h*32+e][d]
__global__ __launch_bounds__(256) void k2_reduce(const float* __restrict__ ctx_part,
                                                 const float* __restrict__ S_part,
                                                 unsigned short* __restrict__ ctxn) {
    __shared__ float Sinv[128];
    const int b     = blockIdx.x >> 3;
    const int chunk = blockIdx.x & 7;            // 8 chunks of 512 elems
    const int tid   = threadIdx.x;
    if (tid < 128) {
        float s = 0.f;
        #pragma unroll
        for (int t = 0; t < TPB_; t++)
            s += S_part[(size_t)(b * TPB_ + t) * 128 + tid];
        Sinv[tid] = 1.0f / s;
    }
    __syncthreads();
    #pragma unroll
    for (int j = 0; j < 2; j++) {
        const int ei = chunk * 512 + j * 256 + tid;   // flat [h][d][e]
        float v = 0.f;
        #pragma unroll
        for (int t = 0; t < TPB_; t++)
            v += ctx_part[((size_t)(b * TPB_ + t) << 12) + ei];
        const int h = ei >> 10, d = (ei >> 5) & 31, e = ei & 31;
        ctxn[(size_t)b * 4096 + (h * 32 + e) * 32 + d] = bf16_rne(v * Sinv[h * 32 + d]);
    }
}

// K3: out2 = ctxn @ qsm per head (K=32), y = Wout @ out2 + bout (K=128), LayerNorm over c.
__global__ __launch_bounds__(256, 4) void k3_out(const unsigned short* __restrict__ qsm,
                                                 const unsigned short* __restrict__ ctxn,
                                                 const unsigned short* __restrict__ wo,
                                                 const float* __restrict__ bout,
                                                 const float* __restrict__ lnw,
                                                 const float* __restrict__ lnb,
                                                 float* __restrict__ out) {
    __shared__ __align__(16) unsigned short o2[64 * 136];    // [n][h*32+e], stride 136

    const int b  = blockIdx.y;
    const int n0 = blockIdx.x * 64;
    const int tid = threadIdx.x;

    const int lane = tid & 63, wv = tid >> 6, l15 = lane & 15, quad = lane >> 4;
    const int nl = wv * 16 + l15;
    const size_t n = (size_t)n0 + nl;

    const float4v zero = {0.f, 0.f, 0.f, 0.f};

    // batch ALL global frag loads for the out2 stage (12 x 16B in flight)
    short8 bq[4], ca[4][2];
    #pragma unroll
    for (int h = 0; h < 4; h++)
        bq[h] = *(const short8*)(qsm + ((size_t)b * N_ + n) * C_ + h * 32 + quad * 8);
    #pragma unroll
    for (int h = 0; h < 4; h++)
        #pragma unroll
        for (int et = 0; et < 2; et++)
            ca[h][et] = *(const short8*)(ctxn + (size_t)b * 4096 + (h * 32 + et * 16 + l15) * 32 + quad * 8);

    #pragma unroll
    for (int h = 0; h < 4; h++) {
        #pragma unroll
        for (int et = 0; et < 2; et++) {
            float4v c4 = __builtin_amdgcn_mfma_f32_16x16x32_bf16(ca[h][et], bq[h], zero, 0, 0, 0);
            short4v s4;
            #pragma unroll
            for (int r = 0; r < 4; r++) s4[r] = (short)bf16_rne(c4[r]);
            *(short4v*)&o2[nl * 136 + h * 32 + et * 16 + quad * 4] = s4;
        }
    }
    __syncthreads();

    short8 bfr[4];                               // B-frags (out2) reused across 8 o-tiles
    #pragma unroll
    for (int kk = 0; kk < 4; kk++)
        bfr[kk] = *(const short8*)&o2[nl * 136 + kk * 32 + quad * 8];

    float4v acc[8];
    #pragma unroll
    for (int ot = 0; ot < 8; ot++) {
        const unsigned short* wp = wo + (ot * 16 + l15) * C_ + quad * 8;
        short8 w[4];
        #pragma unroll
        for (int kk = 0; kk < 4; kk++) w[kk] = *(const short8*)(wp + kk * 32);
        acc[ot] = zero;
        #pragma unroll
        for (int kk = 0; kk < 4; kk++)
            acc[ot] = __builtin_amdgcn_mfma_f32_16x16x32_bf16(w[kk], bfr[kk], acc[ot], 0, 0, 0);
    }

    // bias + LayerNorm over the 128 channels of this column
    float sum = 0.f, sq = 0.f;
    #pragma unroll
    for (int ot = 0; ot < 8; ot++) {
        #pragma unroll
        for (int r = 0; r < 4; r++) {
            const int o = ot * 16 + quad * 4 + r;
            const float y = acc[ot][r] + bout[o];
            acc[ot][r] = y;
            sum += y; sq += y * y;
        }
    }
    sum += __shfl_xor(sum, 16, 64);
    sum += __shfl_xor(sum, 32, 64);
    sq  += __shfl_xor(sq, 16, 64);
    sq  += __shfl_xor(sq, 32, 64);
    const float mean = sum * (1.0f / 128.0f);
    const float var  = sq * (1.0f / 128.0f) - mean * mean;   // biased, matches jnp.var
    const float rstd = rsqrtf(var + 1e-5f);

    #pragma unroll
    for (int ot = 0; ot < 8; ot++) {
        #pragma unroll
        for (int r = 0; r < 4; r++) {
            const int o = ot * 16 + quad * 4 + r;
            out[((size_t)b * C_ + o) * N_ + n] = (acc[ot][r] - mean) * rstd * lnw[o] + lnb[o];
        }
    }
}

extern "C" void kernel_launch(void* const* d_in, const int* in_sizes, int n_in,
                              void* d_out, int out_size, void* d_ws, size_t ws_size,
                              hipStream_t stream) {
    const float* x    = (const float*)d_in[0];
    const float* Wqkv = (const float*)d_in[1];
    const float* Wout = (const float*)d_in[2];
    const float* bout = (const float*)d_in[3];
    const float* lnw  = (const float*)d_in[4];
    const float* lnb  = (const float*)d_in[5];
    float* out = (float*)d_out;

    char* ws = (char*)d_ws;
    unsigned short* wq   = (unsigned short*)(ws + OFF_WQ);
    unsigned short* wo   = (unsigned short*)(ws + OFF_WO);
    float* S_part        = (float*)(ws + OFF_SP);
    float* ctx_part      = (float*)(ws + OFF_CTXP);
    unsigned short* ctxn = (unsigned short*)(ws + OFF_CTXN);
    unsigned short* qsm  = (unsigned short*)(ws + OFF_QSM);

    k0_prep<<<192, 256, 0, stream>>>(Wqkv, Wout, wq, wo);
    k1_qkv<<<dim3(TPB_, B_), 512, 0, stream>>>(x, wq, qsm, ctx_part, S_part);
    k2_reduce<<<B_ * 8, 256, 0, stream>>>(ctx_part, S_part, ctxn);
    k3_out<<<dim3(N_ / 64, B_), 256, 0, stream>>>(qsm, ctxn, wo, bout, lnw, lnb, out);
}

// Round 4
// 273.043 us; speedup vs baseline: 1.1752x; 1.1752x over previous
//
#include <hip/hip_runtime.h>
#include <stdint.h>

// LinearAttention fused: qkv GEMM + dual softmax + linear attention + Wout GEMM + LayerNorm2d
// Shapes: b=32, c=128, n=64*64=4096, heads=4, dim_head=32.
// All GEMMs via v_mfma_f32_16x16x32_bf16 (fp32 accum).
//
// R2: atomic-free (R1 k1 spun ~395us in fp32 atomicAdd CAS loops).
// R3: batched frag loads — but __launch_bounds__(512,4) capped VGPR at 64 ->
//     everything spilled to scratch (+300MB HBM round-trip, k1 108->181us).
// R4: plain __launch_bounds__ (no min-waves clamp — registers up to ~128 are
//     free, occupancy is LDS-capped at 2 blocks/CU); x staging double-buffered
//     (prefetch subtile s+1's 16 HBM loads under subtile s's gemm phase).

constexpr int B_   = 32;
constexpr int C_   = 128;
constexpr int N_   = 4096;
constexpr int O3_  = 384;   // 3*128 qkv rows
constexpr int NSUB = 4;     // 64-wide n-subtiles per k1 block
constexpr int TPB_ = 16;    // k1 blocks per batch (4096 / 256)

using short8  = __attribute__((ext_vector_type(8))) short;
using short4v = __attribute__((ext_vector_type(4))) short;
using float4v = __attribute__((ext_vector_type(4))) float;

__device__ __forceinline__ unsigned short bf16_rne(float f) {
    union { float f; uint32_t u; } v; v.f = f;
    uint32_t u = v.u;
    u += 0x7FFFu + ((u >> 16) & 1u);   // round-to-nearest-even
    return (unsigned short)(u >> 16);
}
__device__ __forceinline__ float bf2f(unsigned short h) {
    union { uint32_t u; float f; } v; v.u = ((uint32_t)h) << 16; return v.f;
}

// workspace layout (bytes)
constexpr size_t OFF_WQ   = 0;          // Wqkv bf16: 384*128*2 = 98304
constexpr size_t OFF_WO   = 98304;      // Wout bf16: 128*128*2 = 32768
constexpr size_t OFF_SP   = 131072;     // S partials [b][16][128] f32: 262144
constexpr size_t OFF_CTXP = 393216;     // ctx partials [b][16][4096] f32: 8388608
constexpr size_t OFF_CTXN = 8781824;    // ctx normalized bf16 [b][h*32+e][d]: 262144
constexpr size_t OFF_QSM  = 9043968;    // q-softmax bf16 [b][n][h*32+d]: 33554432
// total 42,598,400 bytes

__global__ __launch_bounds__(256) void k0_prep(const float* __restrict__ Wqkv,
                                               const float* __restrict__ Wout,
                                               unsigned short* __restrict__ wq,
                                               unsigned short* __restrict__ wo) {
    int t = blockIdx.x * 256 + threadIdx.x;      // grid = 192*256 = 49152
    if (t < O3_ * C_) wq[t] = bf16_rne(Wqkv[t]);
    if (t < C_ * C_)  wo[t] = bf16_rne(Wout[t]);
}

// K1: per (b, 256-wide n-tile): for each 64-subtile: qkv = Wqkv @ x, q-softmax -> qsm,
// exp(k), v -> LDS, context accumulated in registers (MFMA). Partials to global at end.
__global__ __launch_bounds__(512) void k1_qkv(const float* __restrict__ x,
                                              const unsigned short* __restrict__ wq,
                                              unsigned short* __restrict__ qsm,
                                              float* __restrict__ ctx_part,
                                              float* __restrict__ S_part) {
    __shared__ __align__(16) unsigned short xs0[64 * 136];   // [n][c], stride 136 (dbuf A)
    __shared__ __align__(16) unsigned short xs1[64 * 136];   // dbuf B
    __shared__ __align__(16) unsigned short ek[128 * 72];    // [h*32+d][n], stride 72
    __shared__ __align__(16) unsigned short vsh[128 * 72];   // [h*32+e][n]

    const int b    = blockIdx.y;
    const int tblk = blockIdx.x;                 // 0..15
    const int tid  = threadIdx.x;

    const int lane = tid & 63;
    const int wv   = tid >> 6;                   // 0..7
    const int l15  = lane & 15;
    const int quad = lane >> 4;
    const int cw   = wv & 3;                     // n col-tile within the 64
    const int ncol = cw * 16 + l15;
    const bool armA = (wv >> 2) == 0;            // waves 0-3: q+k01; waves 4-7: k23+v

    // staging coords (per-thread fixed)
    const int snl = tid & 63;                    // n within subtile
    const int scg = tid >> 6;                    // c group of 16
    const float* xbase = x + ((size_t)b * C_ + (size_t)scg * 16) * N_ + snl;

    const float4v zero = {0.f, 0.f, 0.f, 0.f};
    float4v cacc[2] = {zero, zero};              // this wave's 2 context tiles
    float s_acc = 0.f;                           // this thread's S partial

    float xv[16];
    auto load_x = [&](int s) {                   // 16 independent HBM loads
        const float* xp = xbase + (tblk * NSUB + s) * 64;
        #pragma unroll
        for (int i = 0; i < 16; i++) xv[i] = xp[(size_t)i * N_];
    };
    auto store_x = [&](unsigned short* xs) {     // convert + LDS store (own slot)
        unsigned short* dst = &xs[snl * 136 + scg * 16];
        #pragma unroll
        for (int i = 0; i < 2; i++) {
            short8 v8;
            #pragma unroll
            for (int j = 0; j < 8; j++) v8[j] = (short)bf16_rne(xv[i * 8 + j]);
            *(short8*)(dst + i * 8) = v8;
        }
    };

    load_x(0);
    store_x(xs0);
    unsigned short* xs_cur = xs0;
    unsigned short* xs_nxt = xs1;

    for (int s = 0; s < NSUB; s++) {
        const int ns = (tblk * NSUB + s) * 64;
        __syncthreads();                         // xs_cur visible; ek/vsh safe to overwrite

        if (s + 1 < NSUB) load_x(s + 1);         // prefetch: stays in flight through gemm

        // B-frags (x) loaded once, reused for all row-pairs: B[k=c][col=n]
        short8 bfx[4];
        #pragma unroll
        for (int kk = 0; kk < 4; kk++)
            bfx[kk] = *(const short8*)&xs_cur[ncol * 136 + kk * 32 + quad * 8];

        // one row-pair GEMM: batched A-frag loads, then 8 MFMAs
        auto gemm_rp = [&](int rp, float4v& acc0, float4v& acc1) {
            const unsigned short* wqp = wq + (rp * 32 + l15) * C_ + quad * 8;
            short8 a0[4], a1[4];
            #pragma unroll
            for (int kk = 0; kk < 4; kk++) {
                a0[kk] = *(const short8*)(wqp + kk * 32);
                a1[kk] = *(const short8*)(wqp + 16 * C_ + kk * 32);
            }
            #pragma unroll
            for (int kk = 0; kk < 4; kk++) {
                acc0 = __builtin_amdgcn_mfma_f32_16x16x32_bf16(a0[kk], bfx[kk], acc0, 0, 0, 0);
                acc1 = __builtin_amdgcn_mfma_f32_16x16x32_bf16(a1[kk], bfx[kk], acc1, 0, 0, 0);
            }
        };
        // C/D layout: col = l15 (n), row = quad*4 + r (acc0: d 0..15, acc1: d 16..31)
        auto q_epi = [&](int h, const float4v& acc0, const float4v& acc1) {
            float e0[4], e1[4], z = 0.f;
            #pragma unroll
            for (int r = 0; r < 4; r++) {
                e0[r] = __expf(acc0[r]); e1[r] = __expf(acc1[r]);
                z += e0[r] + e1[r];
            }
            z += __shfl_xor(z, 16, 64);
            z += __shfl_xor(z, 32, 64);
            const float iz = 1.0f / z;
            unsigned short* qp = qsm + ((size_t)b * N_ + ns + ncol) * C_ + h * 32 + quad * 4;
            short4v s0, s1;
            #pragma unroll
            for (int r = 0; r < 4; r++) {
                s0[r] = (short)bf16_rne(e0[r] * iz);
                s1[r] = (short)bf16_rne(e1[r] * iz);
            }
            *(short4v*)qp = s0;                  // d = quad*4..+3
            *(short4v*)(qp + 16) = s1;           // d = 16+quad*4..+3
        };
        auto k_epi = [&](int h, const float4v& acc0, const float4v& acc1) {
            const int row0 = h * 32 + quad * 4;
            #pragma unroll
            for (int r = 0; r < 4; r++) {
                ek[(row0 + r) * 72 + ncol]      = bf16_rne(__expf(acc0[r]));
                ek[(row0 + 16 + r) * 72 + ncol] = bf16_rne(__expf(acc1[r]));
            }
        };
        auto v_epi = [&](int h, const float4v& acc0, const float4v& acc1) {
            const int row0 = h * 32 + quad * 4;
            #pragma unroll
            for (int r = 0; r < 4; r++) {
                vsh[(row0 + r) * 72 + ncol]      = bf16_rne(acc0[r]);
                vsh[(row0 + 16 + r) * 72 + ncol] = bf16_rne(acc1[r]);
            }
        };

        if (armA) {                              // compile-time rp in each arm
            #pragma unroll
            for (int u = 0; u < 4; u++) {        // q heads 0..3
                float4v acc0 = zero, acc1 = zero;
                gemm_rp(u, acc0, acc1);
                q_epi(u, acc0, acc1);
            }
            #pragma unroll
            for (int u = 0; u < 2; u++) {        // k heads 0,1
                float4v acc0 = zero, acc1 = zero;
                gemm_rp(4 + u, acc0, acc1);
                k_epi(u, acc0, acc1);
            }
        } else {
            #pragma unroll
            for (int u = 0; u < 2; u++) {        // k heads 2,3
                float4v acc0 = zero, acc1 = zero;
                gemm_rp(6 + u, acc0, acc1);
                k_epi(2 + u, acc0, acc1);
            }
            #pragma unroll
            for (int u = 0; u < 4; u++) {        // v heads 0..3
                float4v acc0 = zero, acc1 = zero;
                gemm_rp(8 + u, acc0, acc1);
                v_epi(u, acc0, acc1);
            }
        }

        if (s + 1 < NSUB) store_x(xs_nxt);       // waits on prefetch; next buffer
        { unsigned short* t = xs_cur; xs_cur = xs_nxt; xs_nxt = t; }
        __syncthreads();                         // ek/vsh (and xs_nxt) ready

        // context: cacc[d][e] += sum_n expk[d][n] * v[e][n]  (MFMA, K = 64)
        #pragma unroll
        for (int i = 0; i < 2; i++) {
            const int t = wv * 2 + i;            // 16 tiles: (h, d-tile, e-tile)
            const int h = t >> 2, dt = (t >> 1) & 1, et = t & 1;
            const unsigned short* ap = &ek[(h * 32 + dt * 16 + l15) * 72 + quad * 8];
            const unsigned short* bp = &vsh[(h * 32 + et * 16 + l15) * 72 + quad * 8];
            #pragma unroll
            for (int kk = 0; kk < 2; kk++) {
                short8 a  = *(const short8*)(ap + kk * 32);
                short8 bb = *(const short8*)(bp + kk * 32);
                cacc[i] = __builtin_amdgcn_mfma_f32_16x16x32_bf16(a, bb, cacc[i], 0, 0, 0);
            }
        }

        {   // S partial sums (same bf16 values the context MFMA consumed)
            const int row = tid >> 2;            // 0..127 = h*32+d
            const int sub = tid & 3;
            const unsigned short* ep = &ek[row * 72 + sub * 16];
            short8 e0 = *(const short8*)ep;      // 2 x ds_read_b128
            short8 e1 = *(const short8*)(ep + 8);
            float ss = 0.f;
            #pragma unroll
            for (int j = 0; j < 8; j++) ss += bf2f((unsigned short)e0[j]) + bf2f((unsigned short)e1[j]);
            s_acc += ss;
        }
    }

    // write-out: plain stores, no atomics
    float* cp_base = ctx_part + ((size_t)(b * TPB_ + tblk) << 12);
    #pragma unroll
    for (int i = 0; i < 2; i++) {
        const int t = wv * 2 + i;
        const int h = t >> 2, dt = (t >> 1) & 1, et = t & 1;
        float* cp = cp_base + ((h * 32 + dt * 16 + quad * 4) * 32 + et * 16 + l15);
        #pragma unroll
        for (int r = 0; r < 4; r++) cp[r * 32] = cacc[i][r];
    }
    {
        float ss = s_acc;
        ss += __shfl_xor(ss, 1, 64);
        ss += __shfl_xor(ss, 2, 64);
        if ((tid & 3) == 0)
            S_part[(size_t)(b * TPB_ + tblk) * 128 + (tid >> 2)] = ss;
    }
}

// K2: reduce 16 partials per b, fold 1/S, emit bf16 context in A-frag layout [b][h*32+e][d]
__global__ __launch_bounds__(256) void k2_reduce(const float* __restrict__ ctx_part,
                                                 const float* __restrict__ S_part,
                                                 unsigned short* __restrict__ ctxn) {
    __shared__ float Sinv[128];
    const int b     = blockIdx.x >> 3;
    const int chunk = blockIdx.x & 7;            // 8 chunks of 512 elems
    const int tid   = threadIdx.x;
    if (tid < 128) {
        float s = 0.f;
        #pragma unroll
        for (int t = 0; t < TPB_; t++)
            s += S_part[(size_t)(b * TPB_ + t) * 128 + tid];
        Sinv[tid] = 1.0f / s;
    }
    __syncthreads();
    #pragma unroll
    for (int j = 0; j < 2; j++) {
        const int ei = chunk * 512 + j * 256 + tid;   // flat [h][d][e]
        float v = 0.f;
        #pragma unroll
        for (int t = 0; t < TPB_; t++)
            v += ctx_part[((size_t)(b * TPB_ + t) << 12) + ei];
        const int h = ei >> 10, d = (ei >> 5) & 31, e = ei & 31;
        ctxn[(size_t)b * 4096 + (h * 32 + e) * 32 + d] = bf16_rne(v * Sinv[h * 32 + d]);
    }
}

// K3: out2 = ctxn @ qsm per head (K=32), y = Wout @ out2 + bout (K=128), LayerNorm over c.
__global__ __launch_bounds__(256) void k3_out(const unsigned short* __restrict__ qsm,
                                              const unsigned short* __restrict__ ctxn,
                                              const unsigned short* __restrict__ wo,
                                              const float* __restrict__ bout,
                                              const float* __restrict__ lnw,
                                              const float* __restrict__ lnb,
                                              float* __restrict__ out) {
    __shared__ __align__(16) unsigned short o2[64 * 136];    // [n][h*32+e], stride 136

    const int b  = blockIdx.y;
    const int n0 = blockIdx.x * 64;
    const int tid = threadIdx.x;

    const int lane = tid & 63, wv = tid >> 6, l15 = lane & 15, quad = lane >> 4;
    const int nl = wv * 16 + l15;
    const size_t n = (size_t)n0 + nl;

    const float4v zero = {0.f, 0.f, 0.f, 0.f};

    // batch ALL global frag loads for the out2 stage (12 x 16B in flight)
    short8 bq[4], ca[4][2];
    #pragma unroll
    for (int h = 0; h < 4; h++)
        bq[h] = *(const short8*)(qsm + ((size_t)b * N_ + n) * C_ + h * 32 + quad * 8);
    #pragma unroll
    for (int h = 0; h < 4; h++)
        #pragma unroll
        for (int et = 0; et < 2; et++)
            ca[h][et] = *(const short8*)(ctxn + (size_t)b * 4096 + (h * 32 + et * 16 + l15) * 32 + quad * 8);

    #pragma unroll
    for (int h = 0; h < 4; h++) {
        #pragma unroll
        for (int et = 0; et < 2; et++) {
            float4v c4 = __builtin_amdgcn_mfma_f32_16x16x32_bf16(ca[h][et], bq[h], zero, 0, 0, 0);
            short4v s4;
            #pragma unroll
            for (int r = 0; r < 4; r++) s4[r] = (short)bf16_rne(c4[r]);
            *(short4v*)&o2[nl * 136 + h * 32 + et * 16 + quad * 4] = s4;
        }
    }
    __syncthreads();

    short8 bfr[4];                               // B-frags (out2) reused across 8 o-tiles
    #pragma unroll
    for (int kk = 0; kk < 4; kk++)
        bfr[kk] = *(const short8*)&o2[nl * 136 + kk * 32 + quad * 8];

    float4v acc[8];
    #pragma unroll
    for (int ot = 0; ot < 8; ot++) {
        const unsigned short* wp = wo + (ot * 16 + l15) * C_ + quad * 8;
        short8 w[4];
        #pragma unroll
        for (int kk = 0; kk < 4; kk++) w[kk] = *(const short8*)(wp + kk * 32);
        acc[ot] = zero;
        #pragma unroll
        for (int kk = 0; kk < 4; kk++)
            acc[ot] = __builtin_amdgcn_mfma_f32_16x16x32_bf16(w[kk], bfr[kk], acc[ot], 0, 0, 0);
    }

    // bias + LayerNorm over the 128 channels of this column
    float sum = 0.f, sq = 0.f;
    #pragma unroll
    for (int ot = 0; ot < 8; ot++) {
        #pragma unroll
        for (int r = 0; r < 4; r++) {
            const int o = ot * 16 + quad * 4 + r;
            const float y = acc[ot][r] + bout[o];
            acc[ot][r] = y;
            sum += y; sq += y * y;
        }
    }
    sum += __shfl_xor(sum, 16, 64);
    sum += __shfl_xor(sum, 32, 64);
    sq  += __shfl_xor(sq, 16, 64);
    sq  += __shfl_xor(sq, 32, 64);
    const float mean = sum * (1.0f / 128.0f);
    const float var  = sq * (1.0f / 128.0f) - mean * mean;   // biased, matches jnp.var
    const float rstd = rsqrtf(var + 1e-5f);

    #pragma unroll
    for (int ot = 0; ot < 8; ot++) {
        #pragma unroll
        for (int r = 0; r < 4; r++) {
            const int o = ot * 16 + quad * 4 + r;
            out[((size_t)b * C_ + o) * N_ + n] = (acc[ot][r] - mean) * rstd * lnw[o] + lnb[o];
        }
    }
}

extern "C" void kernel_launch(void* const* d_in, const int* in_sizes, int n_in,
                              void* d_out, int out_size, void* d_ws, size_t ws_size,
                              hipStream_t stream) {
    const float* x    = (const float*)d_in[0];
    const float* Wqkv = (const float*)d_in[1];
    const float* Wout = (const float*)d_in[2];
    const float* bout = (const float*)d_in[3];
    const float* lnw  = (const float*)d_in[4];
    const float* lnb  = (const float*)d_in[5];
    float* out = (float*)d_out;

    char* ws = (char*)d_ws;
    unsigned short* wq   = (unsigned short*)(ws + OFF_WQ);
    unsigned short* wo   = (unsigned short*)(ws + OFF_WO);
    float* S_part        = (float*)(ws + OFF_SP);
    float* ctx_part      = (float*)(ws + OFF_CTXP);
    unsigned short* ctxn = (unsigned short*)(ws + OFF_CTXN);
    unsigned short* qsm  = (unsigned short*)(ws + OFF_QSM);

    k0_prep<<<192, 256, 0, stream>>>(Wqkv, Wout, wq, wo);
    k1_qkv<<<dim3(TPB_, B_), 512, 0, stream>>>(x, wq, qsm, ctx_part, S_part);
    k2_reduce<<<B_ * 8, 256, 0, stream>>>(ctx_part, S_part, ctxn);
    k3_out<<<dim3(N_ / 64, B_), 256, 0, stream>>>(qsm, ctxn, wo, bout, lnw, lnb, out);
}

// Round 5
// 180.881 us; speedup vs baseline: 1.7740x; 1.5095x over previous
//
#include <hip/hip_runtime.h>
#include <stdint.h>

// LinearAttention fused: qkv GEMM + dual softmax + linear attention + Wout GEMM + LayerNorm2d
// Shapes: b=32, c=128, n=64*64=4096, heads=4, dim_head=32.
// All GEMMs via v_mfma_f32_16x16x32_bf16 (fp32 accum).
//
// R2: atomic-free (R1 k1 spun ~395us in fp32 atomicAdd CAS loops).
// R3: __launch_bounds__(512,4) capped VGPR at 64 -> scratch spill storm.
// R4: spill reduced but VGPR pinned at 128-cap; dbuf LDS cost a residency. k1 ~invariant
//     108-131us across R2/R4 with all pipes <12% => dominant cost is wq fragment refetch
//     through L1 (every wave re-reads 48KB of wq per subtile; ~786MB L1 traffic).
// R5: k1 rebuilt: 1024-thr blocks, 16 waves. 12 gemm waves own ONE row-pair each with
//     wq frags persistent in 32 VGPRs (loaded once per block); 4 staging waves prefetch
//     x. wq refetch 786MB -> ~25MB. Grid 256 blocks x 8 subtiles.

constexpr int B_   = 32;
constexpr int C_   = 128;
constexpr int N_   = 4096;
constexpr int O3_  = 384;   // 3*128 qkv rows
constexpr int NSUB = 8;     // 64-wide n-subtiles per k1 block
constexpr int TPB_ = 8;     // k1 blocks per batch (4096 / 512)

using short8  = __attribute__((ext_vector_type(8))) short;
using short4v = __attribute__((ext_vector_type(4))) short;
using float4v = __attribute__((ext_vector_type(4))) float;

__device__ __forceinline__ unsigned short bf16_rne(float f) {
    union { float f; uint32_t u; } v; v.f = f;
    uint32_t u = v.u;
    u += 0x7FFFu + ((u >> 16) & 1u);   // round-to-nearest-even
    return (unsigned short)(u >> 16);
}
__device__ __forceinline__ float bf2f(unsigned short h) {
    union { uint32_t u; float f; } v; v.u = ((uint32_t)h) << 16; return v.f;
}

// workspace layout (bytes)
constexpr size_t OFF_WQ   = 0;          // Wqkv bf16: 384*128*2 = 98304
constexpr size_t OFF_WO   = 98304;      // Wout bf16: 128*128*2 = 32768
constexpr size_t OFF_SP   = 131072;     // S partials [b][8][128] f32
constexpr size_t OFF_CTXP = 393216;     // ctx partials [b][8][4096] f32: 4194304
constexpr size_t OFF_CTXN = 8781824;    // ctx normalized bf16 [b][h*32+e][d]: 262144
constexpr size_t OFF_QSM  = 9043968;    // q-softmax bf16 [b][n][h*32+d]: 33554432
// total 42,598,400 bytes

__global__ __launch_bounds__(256) void k0_prep(const float* __restrict__ Wqkv,
                                               const float* __restrict__ Wout,
                                               unsigned short* __restrict__ wq,
                                               unsigned short* __restrict__ wo) {
    int t = blockIdx.x * 256 + threadIdx.x;      // grid = 192*256 = 49152
    if (t < O3_ * C_) wq[t] = bf16_rne(Wqkv[t]);
    if (t < C_ * C_)  wo[t] = bf16_rne(Wout[t]);
}

// K1: per (b, 512-wide n-tile): 16 waves. Waves 0-11: gemm wave w owns qkv row-pair w
// (rows w*32..w*32+31) with wq frags persistent in registers; covers all 64 n-cols.
// Waves 12-15: stage next x subtile (fp32->bf16, double-buffered). All 16 waves then
// run one context-MFMA tile each + S partial sums. Partials to global at end.
__global__ __launch_bounds__(1024) void k1_qkv(const float* __restrict__ x,
                                               const unsigned short* __restrict__ wq,
                                               unsigned short* __restrict__ qsm,
                                               float* __restrict__ ctx_part,
                                               float* __restrict__ S_part) {
    __shared__ __align__(16) unsigned short xs0[64 * 136];   // [n][c], stride 136 (dbuf A)
    __shared__ __align__(16) unsigned short xs1[64 * 136];   // dbuf B
    __shared__ __align__(16) unsigned short ek[128 * 72];    // [h*32+d][n], stride 72
    __shared__ __align__(16) unsigned short vsh[128 * 72];   // [h*32+e][n]

    const int b    = blockIdx.y;
    const int tblk = blockIdx.x;                 // 0..7
    const int tid  = threadIdx.x;

    const int lane = tid & 63;
    const int wv   = tid >> 6;                   // 0..15
    const int l15  = lane & 15;
    const int quad = lane >> 4;

    const float4v zero = {0.f, 0.f, 0.f, 0.f};

    // --- persistent wq fragments for gemm waves (loaded ONCE per block) ---
    short8 wfa[8];                               // [half(0: rows +0..15, 1: +16..31)*4 + kk]
    if (wv < 12) {
        const unsigned short* wqp = wq + (wv * 32 + l15) * C_ + quad * 8;
        #pragma unroll
        for (int kk = 0; kk < 4; kk++) {
            wfa[kk]     = *(const short8*)(wqp + kk * 32);
            wfa[4 + kk] = *(const short8*)(wqp + 16 * C_ + kk * 32);
        }
    }

    // --- staging lanes (waves 12-15): 256 threads, each 32 c-rows of one n ---
    const int sid = tid & 255;                   // for wv>=12: 0..255
    const int snl = sid & 63;                    // n within subtile
    const int scg = sid >> 6;                    // c group of 32
    const float* xbase = x + ((size_t)b * C_ + (size_t)scg * 32) * N_ + snl;
    float xv[32];
    auto load_x = [&](int s) {
        const float* xp = xbase + (tblk * NSUB + s) * 64;
        #pragma unroll
        for (int i = 0; i < 32; i++) xv[i] = xp[(size_t)i * N_];
    };
    auto store_x = [&](unsigned short* xs) {
        unsigned short* dst = &xs[snl * 136 + scg * 32];
        #pragma unroll
        for (int ii = 0; ii < 4; ii++) {
            short8 v8;
            #pragma unroll
            for (int j = 0; j < 8; j++) v8[j] = (short)bf16_rne(xv[ii * 8 + j]);
            *(short8*)(dst + ii * 8) = v8;
        }
    };

    if (wv >= 12) { load_x(0); store_x(xs0); }
    unsigned short* xs_cur = xs0;
    unsigned short* xs_nxt = xs1;

    float4v cacc = zero;                         // this wave's single ctx tile
    float s_acc  = 0.f;
    const int ch  = wv >> 2;                     // ctx tile coords (valid for all 16 wv)
    const int cdt = (wv >> 1) & 1;
    const int cet = wv & 1;

    for (int s = 0; s < NSUB; s++) {
        const int ns = (tblk * NSUB + s) * 64;
        __syncthreads();                         // A: xs_cur staged; ek/vsh free

        if (wv < 12) {
            #pragma unroll
            for (int ct = 0; ct < 4; ct++) {
                short8 bfx[4];
                #pragma unroll
                for (int kk = 0; kk < 4; kk++)
                    bfx[kk] = *(const short8*)&xs_cur[(ct * 16 + l15) * 136 + kk * 32 + quad * 8];
                float4v acc0 = zero, acc1 = zero;
                #pragma unroll
                for (int kk = 0; kk < 4; kk++) {
                    acc0 = __builtin_amdgcn_mfma_f32_16x16x32_bf16(wfa[kk],     bfx[kk], acc0, 0, 0, 0);
                    acc1 = __builtin_amdgcn_mfma_f32_16x16x32_bf16(wfa[4 + kk], bfx[kk], acc1, 0, 0, 0);
                }
                const int ncol = ct * 16 + l15;
                // C/D layout: col = l15, row = quad*4 + r (acc0: rows 0-15, acc1: 16-31)
                if (wv < 4) {                    // q, head h = wv: softmax over d per column
                    float e0[4], e1[4], z = 0.f;
                    #pragma unroll
                    for (int r = 0; r < 4; r++) {
                        e0[r] = __expf(acc0[r]); e1[r] = __expf(acc1[r]);
                        z += e0[r] + e1[r];
                    }
                    z += __shfl_xor(z, 16, 64);
                    z += __shfl_xor(z, 32, 64);
                    const float iz = 1.0f / z;
                    unsigned short* qp = qsm + ((size_t)b * N_ + ns + ncol) * C_ + wv * 32 + quad * 4;
                    short4v s0, s1;
                    #pragma unroll
                    for (int r = 0; r < 4; r++) {
                        s0[r] = (short)bf16_rne(e0[r] * iz);
                        s1[r] = (short)bf16_rne(e1[r] * iz);
                    }
                    *(short4v*)qp = s0;          // d = quad*4..+3
                    *(short4v*)(qp + 16) = s1;   // d = 16+quad*4..+3
                } else if (wv < 8) {             // k, head h = wv-4: exp -> LDS
                    const int row0 = (wv - 4) * 32 + quad * 4;
                    #pragma unroll
                    for (int r = 0; r < 4; r++) {
                        ek[(row0 + r) * 72 + ncol]      = bf16_rne(__expf(acc0[r]));
                        ek[(row0 + 16 + r) * 72 + ncol] = bf16_rne(__expf(acc1[r]));
                    }
                } else {                         // v, head h = wv-8 -> LDS
                    const int row0 = (wv - 8) * 32 + quad * 4;
                    #pragma unroll
                    for (int r = 0; r < 4; r++) {
                        vsh[(row0 + r) * 72 + ncol]      = bf16_rne(acc0[r]);
                        vsh[(row0 + 16 + r) * 72 + ncol] = bf16_rne(acc1[r]);
                    }
                }
            }
        } else {
            if (s + 1 < NSUB) { load_x(s + 1); store_x(xs_nxt); }   // overlaps gemm phase
        }
        __syncthreads();                         // B: ek/vsh ready; xs_nxt staged

        // context: cacc[d][e] += sum_n expk[d][n] * v[e][n]  (one 16x16 tile per wave)
        {
            const unsigned short* ap = &ek[(ch * 32 + cdt * 16 + l15) * 72 + quad * 8];
            const unsigned short* bp = &vsh[(ch * 32 + cet * 16 + l15) * 72 + quad * 8];
            #pragma unroll
            for (int kk = 0; kk < 2; kk++) {
                short8 a  = *(const short8*)(ap + kk * 32);
                short8 bb = *(const short8*)(bp + kk * 32);
                cacc = __builtin_amdgcn_mfma_f32_16x16x32_bf16(a, bb, cacc, 0, 0, 0);
            }
        }
        {   // S partial sums: 1024 threads = 128 rows x 8 threads x 8 elems
            const unsigned short* ep = &ek[(tid >> 3) * 72 + (tid & 7) * 8];
            short8 e0 = *(const short8*)ep;      // one ds_read_b128
            float ss = 0.f;
            #pragma unroll
            for (int j = 0; j < 8; j++) ss += bf2f((unsigned short)e0[j]);
            s_acc += ss;
        }
        { unsigned short* t = xs_cur; xs_cur = xs_nxt; xs_nxt = t; }
    }

    // write-out: plain stores, no atomics
    {
        float* cp = ctx_part + ((size_t)(b * TPB_ + tblk) << 12)
                  + ((ch * 32 + cdt * 16 + quad * 4) * 32 + cet * 16 + l15);
        #pragma unroll
        for (int r = 0; r < 4; r++) cp[r * 32] = cacc[r];
    }
    {
        float ss = s_acc;
        ss += __shfl_xor(ss, 1, 64);
        ss += __shfl_xor(ss, 2, 64);
        ss += __shfl_xor(ss, 4, 64);
        if ((tid & 7) == 0)
            S_part[(size_t)(b * TPB_ + tblk) * 128 + (tid >> 3)] = ss;
    }
}

// K2: reduce 8 partials per b, fold 1/S, emit bf16 context in A-frag layout [b][h*32+e][d]
__global__ __launch_bounds__(256) void k2_reduce(const float* __restrict__ ctx_part,
                                                 const float* __restrict__ S_part,
                                                 unsigned short* __restrict__ ctxn) {
    __shared__ float Sinv[128];
    const int b     = blockIdx.x >> 3;
    const int chunk = blockIdx.x & 7;            // 8 chunks of 512 elems
    const int tid   = threadIdx.x;
    if (tid < 128) {
        float s = 0.f;
        #pragma unroll
        for (int t = 0; t < TPB_; t++)
            s += S_part[(size_t)(b * TPB_ + t) * 128 + tid];
        Sinv[tid] = 1.0f / s;
    }
    __syncthreads();
    #pragma unroll
    for (int j = 0; j < 2; j++) {
        const int ei = chunk * 512 + j * 256 + tid;   // flat [h][d][e]
        float v = 0.f;
        #pragma unroll
        for (int t = 0; t < TPB_; t++)
            v += ctx_part[((size_t)(b * TPB_ + t) << 12) + ei];
        const int h = ei >> 10, d = (ei >> 5) & 31, e = ei & 31;
        ctxn[(size_t)b * 4096 + (h * 32 + e) * 32 + d] = bf16_rne(v * Sinv[h * 32 + d]);
    }
}

// K3: out2 = ctxn @ qsm per head (K=32), y = Wout @ out2 + bout (K=128), LayerNorm over c.
__global__ __launch_bounds__(256) void k3_out(const unsigned short* __restrict__ qsm,
                                              const unsigned short* __restrict__ ctxn,
                                              const unsigned short* __restrict__ wo,
                                              const float* __restrict__ bout,
                                              const float* __restrict__ lnw,
                                              const float* __restrict__ lnb,
                                              float* __restrict__ out) {
    __shared__ __align__(16) unsigned short o2[64 * 136];    // [n][h*32+e], stride 136

    const int b  = blockIdx.y;
    const int n0 = blockIdx.x * 64;
    const int tid = threadIdx.x;

    const int lane = tid & 63, wv = tid >> 6, l15 = lane & 15, quad = lane >> 4;
    const int nl = wv * 16 + l15;
    const size_t n = (size_t)n0 + nl;

    const float4v zero = {0.f, 0.f, 0.f, 0.f};

    // batch ALL global frag loads for the out2 stage (12 x 16B in flight)
    short8 bq[4], ca[4][2];
    #pragma unroll
    for (int h = 0; h < 4; h++)
        bq[h] = *(const short8*)(qsm + ((size_t)b * N_ + n) * C_ + h * 32 + quad * 8);
    #pragma unroll
    for (int h = 0; h < 4; h++)
        #pragma unroll
        for (int et = 0; et < 2; et++)
            ca[h][et] = *(const short8*)(ctxn + (size_t)b * 4096 + (h * 32 + et * 16 + l15) * 32 + quad * 8);

    #pragma unroll
    for (int h = 0; h < 4; h++) {
        #pragma unroll
        for (int et = 0; et < 2; et++) {
            float4v c4 = __builtin_amdgcn_mfma_f32_16x16x32_bf16(ca[h][et], bq[h], zero, 0, 0, 0);
            short4v s4;
            #pragma unroll
            for (int r = 0; r < 4; r++) s4[r] = (short)bf16_rne(c4[r]);
            *(short4v*)&o2[nl * 136 + h * 32 + et * 16 + quad * 4] = s4;
        }
    }
    __syncthreads();

    short8 bfr[4];                               // B-frags (out2) reused across 8 o-tiles
    #pragma unroll
    for (int kk = 0; kk < 4; kk++)
        bfr[kk] = *(const short8*)&o2[nl * 136 + kk * 32 + quad * 8];

    float4v acc[8];
    #pragma unroll
    for (int ot = 0; ot < 8; ot++) {
        const unsigned short* wp = wo + (ot * 16 + l15) * C_ + quad * 8;
        short8 w[4];
        #pragma unroll
        for (int kk = 0; kk < 4; kk++) w[kk] = *(const short8*)(wp + kk * 32);
        acc[ot] = zero;
        #pragma unroll
        for (int kk = 0; kk < 4; kk++)
            acc[ot] = __builtin_amdgcn_mfma_f32_16x16x32_bf16(w[kk], bfr[kk], acc[ot], 0, 0, 0);
    }

    // bias + LayerNorm over the 128 channels of this column
    float sum = 0.f, sq = 0.f;
    #pragma unroll
    for (int ot = 0; ot < 8; ot++) {
        #pragma unroll
        for (int r = 0; r < 4; r++) {
            const int o = ot * 16 + quad * 4 + r;
            const float y = acc[ot][r] + bout[o];
            acc[ot][r] = y;
            sum += y; sq += y * y;
        }
    }
    sum += __shfl_xor(sum, 16, 64);
    sum += __shfl_xor(sum, 32, 64);
    sq  += __shfl_xor(sq, 16, 64);
    sq  += __shfl_xor(sq, 32, 64);
    const float mean = sum * (1.0f / 128.0f);
    const float var  = sq * (1.0f / 128.0f) - mean * mean;   // biased, matches jnp.var
    const float rstd = rsqrtf(var + 1e-5f);

    #pragma unroll
    for (int ot = 0; ot < 8; ot++) {
        #pragma unroll
        for (int r = 0; r < 4; r++) {
            const int o = ot * 16 + quad * 4 + r;
            out[((size_t)b * C_ + o) * N_ + n] = (acc[ot][r] - mean) * rstd * lnw[o] + lnb[o];
        }
    }
}

extern "C" void kernel_launch(void* const* d_in, const int* in_sizes, int n_in,
                              void* d_out, int out_size, void* d_ws, size_t ws_size,
                              hipStream_t stream) {
    const float* x    = (const float*)d_in[0];
    const float* Wqkv = (const float*)d_in[1];
    const float* Wout = (const float*)d_in[2];
    const float* bout = (const float*)d_in[3];
    const float* lnw  = (const float*)d_in[4];
    const float* lnb  = (const float*)d_in[5];
    float* out = (float*)d_out;

    char* ws = (char*)d_ws;
    unsigned short* wq   = (unsigned short*)(ws + OFF_WQ);
    unsigned short* wo   = (unsigned short*)(ws + OFF_WO);
    float* S_part        = (float*)(ws + OFF_SP);
    float* ctx_part      = (float*)(ws + OFF_CTXP);
    unsigned short* ctxn = (unsigned short*)(ws + OFF_CTXN);
    unsigned short* qsm  = (unsigned short*)(ws + OFF_QSM);

    k0_prep<<<192, 256, 0, stream>>>(Wqkv, Wout, wq, wo);
    k1_qkv<<<dim3(TPB_, B_), 1024, 0, stream>>>(x, wq, qsm, ctx_part, S_part);
    k2_reduce<<<B_ * 8, 256, 0, stream>>>(ctx_part, S_part, ctxn);
    k3_out<<<dim3(N_ / 64, B_), 256, 0, stream>>>(qsm, ctxn, wo, bout, lnw, lnb, out);
}